// Round 6
// baseline (1145.184 us; speedup 1.0000x reference)
//
#include <hip/hip_runtime.h>

#define TOKENS 4096
#define DIN    4096
#define DOUT   16384

#define BM 256
#define BN 256
#define BK 64
#define NT (DIN / BK)   // 64 k-tiles

#define X_BYTES ((size_t)TOKENS * DIN * 2)   // 32 MB bf16
#define W_BYTES ((size_t)DOUT   * DIN * 2)   // 128 MB bf16

typedef __attribute__((ext_vector_type(8))) short short8;
typedef __attribute__((ext_vector_type(4))) float f32x4;

// fp32 -> bf16 bits, round-to-nearest-even (inputs finite)
__device__ __forceinline__ unsigned short f2bf(float f) {
    unsigned u = __builtin_bit_cast(unsigned, f);
    u += 0x7fffu + ((u >> 16) & 1u);
    return (unsigned short)(u >> 16);
}

#define GLOAD_LDS16(gptr, lptr)                                                        \
    __builtin_amdgcn_global_load_lds(                                                  \
        (const __attribute__((address_space(1))) unsigned int*)(gptr),                 \
        (__attribute__((address_space(3))) unsigned int*)(lptr), 16, 0, 0)

#define SB0 __builtin_amdgcn_sched_barrier(0)

// ---------------- pre-pass converters (memory-bound) ----------------
__global__ __launch_bounds__(256)
void cvt_x_kernel(const float* __restrict__ in, unsigned short* __restrict__ out) {
    const size_t base = ((size_t)blockIdx.x * 256 + threadIdx.x) * 8;
    const float4 a = *(const float4*)&in[base];
    const float4 b = *(const float4*)&in[base + 4];
    uint4 o;
    o.x = (unsigned)f2bf(a.x) | ((unsigned)f2bf(a.y) << 16);
    o.y = (unsigned)f2bf(a.z) | ((unsigned)f2bf(a.w) << 16);
    o.z = (unsigned)f2bf(b.x) | ((unsigned)f2bf(b.y) << 16);
    o.w = (unsigned)f2bf(b.z) | ((unsigned)f2bf(b.w) << 16);
    *(uint4*)&out[base] = o;
}

__global__ __launch_bounds__(256)
void cvt_w_kernel(const int* __restrict__ in, unsigned short* __restrict__ out) {
    const size_t base = ((size_t)blockIdx.x * 256 + threadIdx.x) * 8;
    const int4 a = *(const int4*)&in[base];
    const int4 b = *(const int4*)&in[base + 4];
    uint4 o;   // int8 values are exact in bf16
    o.x = (unsigned)f2bf((float)a.x) | ((unsigned)f2bf((float)a.y) << 16);
    o.y = (unsigned)f2bf((float)a.z) | ((unsigned)f2bf((float)a.w) << 16);
    o.z = (unsigned)f2bf((float)b.x) | ((unsigned)f2bf((float)b.y) << 16);
    o.w = (unsigned)f2bf((float)b.z) | ((unsigned)f2bf((float)b.w) << 16);
    *(uint4*)&out[base] = o;
}

// ---------------- 256x256 bf16 GEMM, asm ds_read + counted lgkm pipeline ----------------
// 8 waves = 2(M) x 4(N); per-wave output 128x64; BK=64; LDS 2 x (A 32KB + B 32KB).
// LDS linear [buf][A|B][256 rows][8 chunks of 16B]; swizzle on the GLOBAL source:
// phys chunk pc of row r holds global k-chunk gc = pc ^ (r&7); ds_read_b128 of a
// fragment reads chunk (kk*4+quad) ^ (row&7) -> conflict-free (counter = 0).
//
// ROUNDS 2-5 LESSON: every compiler-scheduled variant pins at 38-42% MfmaUtil =
// 2048 busy / ~5343 cyc tile: LDS reads (~2300 port-cyc) and MFMA (2048) fully
// serialize. Compiler either sinks reads to consumers (R4) or drains lgkm fully
// (R2/R5). THIS version takes waitcnt away from the compiler: inline-asm
// ds_read_b128 (opaque -> legalizer inserts no lgkm waits) + hand counted
// s_waitcnt lgkmcnt(N) + sched_barrier(0) after each (rule #18). Ledger
// (<=12 outstanding, HW cap 15):
//   issue g1..g4 (12) | w6 -> M1 | +g5,g6 (12) | w10 -> M2 | +g7 (12) | w8 ->
//   M3,M4 | +g8 (12) | w6 -> M5 | w4 -> M6 | w0 -> M7,M8
// Every wait leaves >=1 MFMA cluster of reads in flight -> LDS port streams
// under the matrix pipe. Buffers: R4's race-free scheme (stage whole t+1 ->
// buf^1 at tile top; one vmcnt(0)+barrier per tile). MFMA order per acc
// identical to R4 -> bit-identical output.
__global__ __launch_bounds__(512, 2)
void gemm_bf16_kernel(const unsigned short* __restrict__ xa,   // [TOKENS][DIN] bf16
                      const unsigned short* __restrict__ wb,   // [DOUT][DIN]  bf16
                      const float* __restrict__ scale,
                      const float* __restrict__ bias,
                      float* __restrict__ out) {
    __shared__ unsigned short smem[2 * 32768];   // 128 KB: [buf][A 16384 | B 16384] shorts

    const int tid  = threadIdx.x;
    const int lane = tid & 63;
    const int wave = tid >> 6;
    const int wm   = wave >> 2;      // 0..1
    const int wn   = wave & 3;       // 0..3
    const int quad = lane >> 4;
    const int l16  = lane & 15;

    // XCD-aware block swizzle (nwg = 1024, divisible by 8 -> bijective)
    const int nwg = (TOKENS / BM) * (DOUT / BN);                       // 16*64 = 1024
    const int wg  = ((int)blockIdx.x & 7) * (nwg >> 3) + ((int)blockIdx.x >> 3);
    const int m0  = (wg & 15) * BM;   // m fastest-varying
    const int n0  = (wg >> 4) * BN;

    // staging: thread handles phys chunks c = i*512+tid of a 128-row half-tile.
    // global source chunk gc = (c&7) ^ (row&7)  (inverse of the read swizzle).
    int gAo[2], gBo[2];
#pragma unroll
    for (int i = 0; i < 2; ++i) {
        const int c  = i * 512 + tid;
        const int r  = c >> 3;             // row within half (0..127)
        const int gc = (c & 7) ^ (r & 7);
        gAo[i] = (m0 + r) * DIN + gc * 8;  // bf16 elem offset (h,k added at stage)
        gBo[i] = (n0 + r) * DIN + gc * 8;
    }

#define STAGE(b, isA, h, kt)                                                             \
    do {                                                                                 \
        const unsigned short* _s = (isA) ? xa : wb;                                      \
        const int _g0 = ((isA) ? gAo[0] : gBo[0]) + (h) * 128 * DIN + (kt) * BK;         \
        const int _g1 = ((isA) ? gAo[1] : gBo[1]) + (h) * 128 * DIN + (kt) * BK;         \
        unsigned short* _d =                                                             \
            &smem[(b) * 32768 + ((isA) ? 0 : 16384) + ((h) * 1024 + wave * 64) * 8];     \
        GLOAD_LDS16(_s + _g0, _d);                                                       \
        GLOAD_LDS16(_s + _g1, _d + 4096);                                                \
    } while (0)

    // ---- LDS byte addresses for asm ds_read (low 32 bits of generic ptr = LDS off)
    const unsigned sbase = (unsigned)(unsigned long long)&smem[0];
    const int cq = quad ^ (l16 & 7);
    // A rows: wm*128 + l16 (+mh*64 via offset imm); B rows: wn*64 + l16 (+nh*32 imm)
    const unsigned aA0_0 = sbase + (unsigned)(((wm * 128 + l16) * 64 + cq * 8) * 2);
    const unsigned aA1_0 = sbase + (unsigned)(((wm * 128 + l16) * 64 + (cq ^ 4) * 8) * 2);
    const unsigned aB0_0 = sbase + 32768u + (unsigned)(((wn * 64 + l16) * 64 + cq * 8) * 2);
    const unsigned aB1_0 = sbase + 32768u + (unsigned)(((wn * 64 + l16) * 64 + (cq ^ 4) * 8) * 2);
    const unsigned aA0_1 = aA0_0 + 65536u;
    const unsigned aA1_1 = aA1_0 + 65536u;
    const unsigned aB0_1 = aB0_0 + 65536u;
    const unsigned aB1_1 = aB1_0 + 65536u;

#define DSR(dst, addr, off)                                                              \
    asm volatile("ds_read_b128 %0, %1 offset:" off : "=v"(dst) : "v"(addr))

#define WAITL(n)                                                                         \
    do {                                                                                 \
        asm volatile("s_waitcnt lgkmcnt(" n ")");                                        \
        __builtin_amdgcn_sched_barrier(0);                                               \
    } while (0)

// 8 MFMAs: one quadrant x one k-half (order identical to R4 -> bit-identical C)
#define MM8(aV, bV, mh, nh)                                                              \
    do {                                                                                 \
        __builtin_amdgcn_s_setprio(1);                                                   \
        _Pragma("unroll") for (int i = 0; i < 4; ++i)                                    \
            _Pragma("unroll") for (int j = 0; j < 2; ++j)                                \
                acc[(mh) * 4 + i][(nh) * 2 + j] = __builtin_amdgcn_mfma_f32_16x16x32_bf16( \
                    aV[i], bV[j], acc[(mh) * 4 + i][(nh) * 2 + j], 0, 0, 0);             \
        __builtin_amdgcn_s_setprio(0);                                                   \
    } while (0)

// One K-tile. AA0/AA1/AB0/AB1 = this buffer's address regs; stages -> other buf.
// Offsets (bytes): A: i*2048, mh half +8192; B: j*2048, nh half +4096.
#define TILE_BODY(AA0, AA1, AB0, AB1, SBUF, tt)                                          \
    do {                                                                                 \
        if ((tt) + 1 < NT) {                                                             \
            STAGE(SBUF, 1, 0, (tt) + 1);                                                 \
            STAGE(SBUF, 1, 1, (tt) + 1);                                                 \
            STAGE(SBUF, 0, 0, (tt) + 1);                                                 \
            STAGE(SBUF, 0, 1, (tt) + 1);                                                 \
        }                                                                                \
        SB0;                                                                             \
        short8 a0k0[4], a1k0[4], a1k1[4], a0k1[4];                                       \
        short8 b0k0[2], b1k0[2], b0k1[2], b1k1[2];                                       \
        DSR(a0k0[0], AA0, "0");     DSR(a0k0[1], AA0, "2048");                           \
        DSR(a0k0[2], AA0, "4096");  DSR(a0k0[3], AA0, "6144");      /* g1 */             \
        DSR(b0k0[0], AB0, "0");     DSR(b0k0[1], AB0, "2048");      /* g2 */             \
        DSR(b1k0[0], AB0, "4096");  DSR(b1k0[1], AB0, "6144");      /* g3 */             \
        DSR(a1k0[0], AA0, "8192");  DSR(a1k0[1], AA0, "10240");                          \
        DSR(a1k0[2], AA0, "12288"); DSR(a1k0[3], AA0, "14336");     /* g4 -> 12 out */   \
        WAITL("6");                 /* g1,g2 done */                                     \
        MM8(a0k0, b0k0, 0, 0);      /* M1 */                                             \
        DSR(a1k1[0], AA1, "8192");  DSR(a1k1[1], AA1, "10240");                          \
        DSR(a1k1[2], AA1, "12288"); DSR(a1k1[3], AA1, "14336");     /* g5 */             \
        DSR(b0k1[0], AB1, "0");     DSR(b0k1[1], AB1, "2048");      /* g6 -> 12 out */   \
        WAITL("10");                /* g3 done */                                        \
        MM8(a0k0, b1k0, 0, 1);      /* M2 */                                             \
        DSR(b1k1[0], AB1, "4096");  DSR(b1k1[1], AB1, "6144");      /* g7 -> 12 out */   \
        WAITL("8");                 /* g4 done */                                        \
        MM8(a1k0, b1k0, 1, 1);      /* M3 */                                             \
        MM8(a1k0, b0k0, 1, 0);      /* M4 */                                             \
        DSR(a0k1[0], AA1, "0");     DSR(a0k1[1], AA1, "2048");                           \
        DSR(a0k1[2], AA1, "4096");  DSR(a0k1[3], AA1, "6144");      /* g8 -> 12 out */   \
        WAITL("6");                 /* g5,g6 done */                                     \
        MM8(a1k1, b0k1, 1, 0);      /* M5 */                                             \
        WAITL("4");                 /* g7 done */                                        \
        MM8(a1k1, b1k1, 1, 1);      /* M6 */                                             \
        WAITL("0");                 /* g8 done; lgkm clean at barrier */                 \
        MM8(a0k1, b1k1, 0, 1);      /* M7 */                                             \
        MM8(a0k1, b0k1, 0, 0);      /* M8 */                                             \
        asm volatile("s_waitcnt vmcnt(0)" ::: "memory");                                 \
        __builtin_amdgcn_s_barrier();                                                    \
    } while (0)

    // ---- prologue: stage tile0 into buf0, drain, publish ----
    STAGE(0, 1, 0, 0);
    STAGE(0, 1, 1, 0);
    STAGE(0, 0, 0, 0);
    STAGE(0, 0, 1, 0);

    f32x4 acc[8][4];
#pragma unroll
    for (int i = 0; i < 8; ++i)
#pragma unroll
        for (int j = 0; j < 4; ++j)
            acc[i][j] = (f32x4){0.f, 0.f, 0.f, 0.f};

    asm volatile("s_waitcnt vmcnt(0)" ::: "memory");
    __builtin_amdgcn_s_barrier();

    for (int t = 0; t < NT; t += 2) {
        TILE_BODY(aA0_0, aA1_0, aB0_0, aB1_0, 1, t);       // compute buf0, stage -> buf1
        TILE_BODY(aA0_1, aA1_1, aB0_1, aB1_1, 0, t + 1);   // compute buf1, stage -> buf0
    }

#undef STAGE
#undef DSR
#undef WAITL
#undef MM8
#undef TILE_BODY

    // ---- epilogue: C/D col=l16 (n), row=quad*4+r (m); fuse scale+bias ----
#pragma unroll
    for (int aj = 0; aj < 4; ++aj) {
        const int col = n0 + wn * 64 + aj * 16 + l16;
        const float s = scale[col];
        const float b = bias[col];
#pragma unroll
        for (int ai = 0; ai < 8; ++ai) {
            const int row0 = m0 + wm * 128 + ai * 16 + quad * 4;
#pragma unroll
            for (int r = 0; r < 4; ++r)
                out[(size_t)(row0 + r) * DOUT + col] = acc[ai][aj][r] * s + b;
        }
    }
}

// ---------------- fallback (round-1 kernel, used only if ws too small) ----------------
#define FBM 128
#define FBN 128
#define FBK 32
#define LDSS 40
__global__ __launch_bounds__(256, 2)
void gemm_fallback_kernel(const float* __restrict__ x, const int* __restrict__ qw,
                          const float* __restrict__ scale, const float* __restrict__ bias,
                          float* __restrict__ out) {
    __shared__ unsigned short As[FBM * LDSS];
    __shared__ unsigned short Bs[FBN * LDSS];
    const int tid = threadIdx.x, lane = tid & 63, wave = tid >> 6;
    const int wm = wave >> 1, wn = wave & 1, quad = lane >> 4, l16 = lane & 15;
    const int m0 = blockIdx.x * FBM, n0 = blockIdx.y * FBN;
    const int srow = tid >> 3, scol = (tid & 7) * 4;
    f32x4 acc[4][4];
#pragma unroll
    for (int i = 0; i < 4; ++i)
#pragma unroll
        for (int j = 0; j < 4; ++j) acc[i][j] = (f32x4){0.f, 0.f, 0.f, 0.f};
    for (int k0 = 0; k0 < DIN; k0 += FBK) {
        __syncthreads();
#pragma unroll
        for (int p = 0; p < 4; ++p) {
            const int r = p * 32 + srow;
            const float4 v = *(const float4*)&x[(size_t)(m0 + r) * DIN + k0 + scol];
            const unsigned a01 = (unsigned)f2bf(v.x) | ((unsigned)f2bf(v.y) << 16);
            const unsigned a23 = (unsigned)f2bf(v.z) | ((unsigned)f2bf(v.w) << 16);
            *(unsigned long long*)&As[r * LDSS + scol] =
                (unsigned long long)a01 | ((unsigned long long)a23 << 32);
        }
#pragma unroll
        for (int p = 0; p < 4; ++p) {
            const int r = p * 32 + srow;
            const int4 v = *(const int4*)&qw[(size_t)(n0 + r) * DIN + k0 + scol];
            const unsigned b01 = (unsigned)f2bf((float)v.x) | ((unsigned)f2bf((float)v.y) << 16);
            const unsigned b23 = (unsigned)f2bf((float)v.z) | ((unsigned)f2bf((float)v.w) << 16);
            *(unsigned long long*)&Bs[r * LDSS + scol] =
                (unsigned long long)b01 | ((unsigned long long)b23 << 32);
        }
        __syncthreads();
        short8 af[4], bfv[4];
#pragma unroll
        for (int i = 0; i < 4; ++i)
            af[i] = *(const short8*)&As[(wm * 64 + i * 16 + l16) * LDSS + quad * 8];
#pragma unroll
        for (int j = 0; j < 4; ++j)
            bfv[j] = *(const short8*)&Bs[(wn * 64 + j * 16 + l16) * LDSS + quad * 8];
#pragma unroll
        for (int i = 0; i < 4; ++i)
#pragma unroll
            for (int j = 0; j < 4; ++j)
                acc[i][j] = __builtin_amdgcn_mfma_f32_16x16x32_bf16(af[i], bfv[j], acc[i][j], 0, 0, 0);
    }
#pragma unroll
    for (int j = 0; j < 4; ++j) {
        const int col = n0 + wn * 64 + j * 16 + l16;
        const float s = scale[col], b = bias[col];
#pragma unroll
        for (int i = 0; i < 4; ++i) {
            const int row0 = m0 + wm * 64 + i * 16 + quad * 4;
#pragma unroll
            for (int r = 0; r < 4; ++r)
                out[(size_t)(row0 + r) * DOUT + col] = acc[i][j][r] * s + b;
        }
    }
}

extern "C" void kernel_launch(void* const* d_in, const int* in_sizes, int n_in,
                              void* d_out, int out_size, void* d_ws, size_t ws_size,
                              hipStream_t stream) {
    const float* x     = (const float*)d_in[0];
    const int*   qw    = (const int*)d_in[1];
    const float* scale = (const float*)d_in[2];
    const float* bias  = (const float*)d_in[3];
    float*       out   = (float*)d_out;

    if (ws_size >= X_BYTES + W_BYTES) {
        unsigned short* x_bf = (unsigned short*)d_ws;
        unsigned short* w_bf = (unsigned short*)((char*)d_ws + X_BYTES);
        cvt_x_kernel<<<dim3((TOKENS * DIN) / (256 * 8)), dim3(256), 0, stream>>>(x, x_bf);
        cvt_w_kernel<<<dim3((DOUT * DIN) / (256 * 8)), dim3(256), 0, stream>>>(qw, w_bf);
        gemm_bf16_kernel<<<dim3((TOKENS / BM) * (DOUT / BN)), dim3(512), 0, stream>>>(
            x_bf, w_bf, scale, bias, out);
    } else {
        gemm_fallback_kernel<<<dim3(TOKENS / FBM, DOUT / FBN), dim3(256), 0, stream>>>(
            x, qw, scale, bias, out);
    }
}